// Round 3
// baseline (159.573 us; speedup 1.0000x reference)
//
#include <hip/hip_runtime.h>
#include <stdint.h>

#define NIMG     128
#define NPROP    2000
#define NGT      100
#define NALL     2100   // NPROP + NGT
#define NSAMPLE  512
#define MAXPOS   128
#define NNEG     384
#define NCHUNK   9      // 9*256 = 2304 >= 2100

#define SAMP_OFF  (NIMG * NSAMPLE * 4)            // 262144
#define MATCH_OFF (SAMP_OFF + NIMG * NSAMPLE)     // 327680

// ws layout (u32 elements): maskarg[NIMG*NALL] | rank[NIMG*NALL]  (~2.1 MB)

// ---------------- kernel A: IoU -> mask / argmax ----------------
__global__ __launch_bounds__(256) void iou_kernel(
    const float* __restrict__ rois, const float* __restrict__ scores,
    const float* __restrict__ gts, unsigned int* __restrict__ maskarg)
{
    __shared__ float s_gt[NGT * 4];
    __shared__ float s_ga[NGT];
    const int img = blockIdx.y;
    const int tid = threadIdx.x;

    for (int i = tid; i < NGT * 4; i += 256)
        s_gt[i] = gts[(size_t)img * NGT * 4 + i];
    __syncthreads();
    for (int g = tid; g < NGT; g += 256) {
        float w = fmaxf(s_gt[g * 4 + 2] - s_gt[g * 4 + 0], 0.0f);
        float h = fmaxf(s_gt[g * 4 + 3] - s_gt[g * 4 + 1], 0.0f);
        s_ga[g] = w * h;
    }
    __syncthreads();

    const int i = blockIdx.x * 256 + tid;
    if (i >= NALL) return;

    float x0, y0, x1, y1, sc;
    if (i < NPROP) {
        const float* p = rois + ((size_t)img * NPROP + i) * 4;
        x0 = p[0]; y0 = p[1]; x1 = p[2]; y1 = p[3];
        sc = scores[(size_t)img * NPROP + i];
    } else {
        int g = i - NPROP;
        x0 = s_gt[g * 4 + 0]; y0 = s_gt[g * 4 + 1];
        x1 = s_gt[g * 4 + 2]; y1 = s_gt[g * 4 + 3];
        sc = 1.0f;
    }
    float aw = fmaxf(x1 - x0, 0.0f);
    float ah = fmaxf(y1 - y0, 0.0f);
    float area_a = aw * ah;
    float best = -1.0f;
    int barg = 0;
    for (int g = 0; g < NGT; ++g) {
        float tlx = fmaxf(x0, s_gt[g * 4 + 0]);
        float tly = fmaxf(y0, s_gt[g * 4 + 1]);
        float brx = fminf(x1, s_gt[g * 4 + 2]);
        float bry = fminf(y1, s_gt[g * 4 + 3]);
        float iw = fmaxf(brx - tlx, 0.0f);
        float ih = fmaxf(bry - tly, 0.0f);
        float inter = iw * ih;
        float uni = area_a + s_ga[g] - inter;
        float iou = (uni > 0.0f) ? (inter / uni) : 0.0f;
        if (iou > best) { best = iou; barg = g; }   // first-max tie-break
    }
    unsigned int m = 2;
    if (sc < 0.0f) m = 0;
    if (best >= 0.5f) m = 3;   // overrides score<0, per reference order
    maskarg[(size_t)img * NALL + i] = (m << 8) | (unsigned int)barg;
}

// ---------------- kernel B: rank by counting (stable argsort) ----------------
__global__ __launch_bounds__(256) void rank_kernel(
    const float* __restrict__ rnd, unsigned int* __restrict__ rank)
{
    __shared__ __align__(16) unsigned long long s_keys[NALL];
    const int img = blockIdx.y;
    const int tid = threadIdx.x;

    for (int i = tid; i < NALL; i += 256) {
        unsigned int bits = __float_as_uint(rnd[(size_t)img * NALL + i]);
        s_keys[i] = ((unsigned long long)bits << 32) | (unsigned int)i;
    }
    __syncthreads();

    const int i = blockIdx.x * 256 + tid;
    if (i >= NALL) return;

    const unsigned long long my = s_keys[i];
    int cnt = 0;
    // wave-uniform LDS reads -> broadcast, conflict-free
    #pragma unroll 4
    for (int j = 0; j < NALL; j += 2) {
        unsigned long long a = s_keys[j];
        unsigned long long b = s_keys[j + 1];
        cnt += (a < my);
        cnt += (b < my);
    }
    rank[(size_t)img * NALL + i] = (unsigned int)cnt;   // unique in [0, NALL)
}

// ---------------- kernel C: permute + dual stable selection ----------------
#define CTHREADS 1024
__global__ __launch_bounds__(CTHREADS) void select_kernel(
    const float* __restrict__ rois, const float* __restrict__ gts,
    const unsigned int* __restrict__ maskarg, const unsigned int* __restrict__ rank,
    float* __restrict__ out)
{
    __shared__ unsigned short s_perm[NALL];
    __shared__ unsigned char s_mask[NALL];
    __shared__ unsigned char s_argb[NALL];
    __shared__ float s_gt[NGT * 4];
    __shared__ int s_c0[CTHREADS], s_c1[CTHREADS], s_c2[CTHREADS];

    const int img = blockIdx.x;
    const int tid = threadIdx.x;

    for (int i = tid; i < NGT * 4; i += CTHREADS)
        s_gt[i] = gts[(size_t)img * NGT * 4 + i];
    for (int i = tid; i < NALL; i += CTHREADS) {
        unsigned int ma = maskarg[(size_t)img * NALL + i];
        s_mask[i] = (unsigned char)(ma >> 8);
        s_argb[i] = (unsigned char)(ma & 0xFF);
        unsigned int r = rank[(size_t)img * NALL + i];
        s_perm[r] = (unsigned short)i;
    }
    __syncthreads();

    // ---- phase 3: top selection (priority 3 > 2 > 0) over [0, NALL) ----
    {
        const int C = 3;   // 1024*3 = 3072 >= 2100
        int p0 = tid * C;
        int p1 = min(p0 + C, NALL);
        int c0 = 0, c1 = 0, c2 = 0;
        for (int p = p0; p < p1; ++p) {
            unsigned char m = s_mask[s_perm[p]];
            if (m == 3) ++c0; else if (m == 2) ++c1; else ++c2;
        }
        s_c0[tid] = c0; s_c1[tid] = c1; s_c2[tid] = c2;
        __syncthreads();
        for (int d = 1; d < CTHREADS; d <<= 1) {   // Hillis-Steele inclusive scan
            int a0 = (tid >= d) ? s_c0[tid - d] : 0;
            int a1 = (tid >= d) ? s_c1[tid - d] : 0;
            int a2 = (tid >= d) ? s_c2[tid - d] : 0;
            __syncthreads();
            s_c0[tid] += a0; s_c1[tid] += a1; s_c2[tid] += a2;
            __syncthreads();
        }
        int tot0 = s_c0[CTHREADS - 1];
        int tot1 = s_c1[CTHREADS - 1];
        int r0 = s_c0[tid] - c0;                 // exclusive prefixes
        int r1 = tot0 + s_c1[tid] - c1;
        int r2 = tot0 + tot1 + s_c2[tid] - c2;
        for (int p = p0; p < p1; ++p) {
            unsigned int orig = s_perm[p];
            unsigned char m = s_mask[orig];
            int slot; float samp;
            if (m == 3)      { slot = r0++; samp = 1.0f; }
            else if (m == 2) { slot = r1++; samp = -1.0f; }
            else             { slot = r2++; samp = 0.0f; }
            if (slot < MAXPOS) {
                float bx0, by0, bx1, by1;
                if (orig < NPROP) {
                    const float* p4 = rois + ((size_t)img * NPROP + orig) * 4;
                    bx0 = p4[0]; by0 = p4[1]; bx1 = p4[2]; by1 = p4[3];
                } else {
                    int g = orig - NPROP;
                    bx0 = s_gt[g * 4 + 0]; by0 = s_gt[g * 4 + 1];
                    bx1 = s_gt[g * 4 + 2]; by1 = s_gt[g * 4 + 3];
                }
                size_t rb = ((size_t)img * NSAMPLE + slot) * 4;
                out[rb + 0] = bx0; out[rb + 1] = by0;
                out[rb + 2] = bx1; out[rb + 3] = by1;
                out[SAMP_OFF  + (size_t)img * NSAMPLE + slot] = samp;
                out[MATCH_OFF + (size_t)img * NSAMPLE + slot] = (float)s_argb[orig];
            }
        }
        __syncthreads();
    }

    // ---- phase 4: bottom selection (priority 2 > 3 > 0) over [MAXPOS, NALL) ----
    {
        const int C = 2;   // 1024*2 = 2048 >= 1972
        int p0 = MAXPOS + tid * C;
        int p1 = min(p0 + C, NALL);
        int c0 = 0, c1 = 0, c2 = 0;
        for (int p = p0; p < p1; ++p) {
            unsigned char m = s_mask[s_perm[p]];
            if (m == 2) ++c0; else if (m == 3) ++c1; else ++c2;
        }
        s_c0[tid] = c0; s_c1[tid] = c1; s_c2[tid] = c2;
        __syncthreads();
        for (int d = 1; d < CTHREADS; d <<= 1) {
            int a0 = (tid >= d) ? s_c0[tid - d] : 0;
            int a1 = (tid >= d) ? s_c1[tid - d] : 0;
            int a2 = (tid >= d) ? s_c2[tid - d] : 0;
            __syncthreads();
            s_c0[tid] += a0; s_c1[tid] += a1; s_c2[tid] += a2;
            __syncthreads();
        }
        int tot0 = s_c0[CTHREADS - 1];
        int tot1 = s_c1[CTHREADS - 1];
        int r0 = s_c0[tid] - c0;
        int r1 = tot0 + s_c1[tid] - c1;
        int r2 = tot0 + tot1 + s_c2[tid] - c2;
        for (int p = p0; p < p1; ++p) {
            unsigned int orig = s_perm[p];
            unsigned char m = s_mask[orig];
            int slot; float samp;
            if (m == 2)      { slot = r0++; samp = -1.0f; }   // mask2: 2->4, highest prio
            else if (m == 3) { slot = r1++; samp = 1.0f; }
            else             { slot = r2++; samp = 0.0f; }
            if (slot < NNEG) {
                int oslot = MAXPOS + slot;
                float bx0, by0, bx1, by1;
                if (orig < NPROP) {
                    const float* p4 = rois + ((size_t)img * NPROP + orig) * 4;
                    bx0 = p4[0]; by0 = p4[1]; bx1 = p4[2]; by1 = p4[3];
                } else {
                    int g = orig - NPROP;
                    bx0 = s_gt[g * 4 + 0]; by0 = s_gt[g * 4 + 1];
                    bx1 = s_gt[g * 4 + 2]; by1 = s_gt[g * 4 + 3];
                }
                size_t rb = ((size_t)img * NSAMPLE + oslot) * 4;
                out[rb + 0] = bx0; out[rb + 1] = by0;
                out[rb + 2] = bx1; out[rb + 3] = by1;
                out[SAMP_OFF  + (size_t)img * NSAMPLE + oslot] = samp;
                out[MATCH_OFF + (size_t)img * NSAMPLE + oslot] = (float)s_argb[orig];
            }
        }
    }
}

extern "C" void kernel_launch(void* const* d_in, const int* in_sizes, int n_in,
                              void* d_out, int out_size, void* d_ws, size_t ws_size,
                              hipStream_t stream) {
    const float* rois   = (const float*)d_in[0];
    const float* scores = (const float*)d_in[1];
    const float* gts    = (const float*)d_in[2];
    const float* rnd    = (const float*)d_in[3];
    unsigned int* maskarg = (unsigned int*)d_ws;
    unsigned int* rank    = maskarg + (size_t)NIMG * NALL;

    dim3 gridA(NCHUNK, NIMG);
    iou_kernel<<<gridA, 256, 0, stream>>>(rois, scores, gts, maskarg);
    rank_kernel<<<gridA, 256, 0, stream>>>(rnd, rank);
    select_kernel<<<NIMG, CTHREADS, 0, stream>>>(rois, gts, maskarg, rank, (float*)d_out);
}